// Round 5
// baseline (1391.197 us; speedup 1.0000x reference)
//
#include <hip/hip_runtime.h>
#include <math.h>

#define N_NODES 50000
#define N_EDGES 800000
#define F 128
#define NBUCKETS 1563        // ceil(50000/32) buckets of 32 dst nodes
#define BCAP 896             // avg 512 edges/bucket, sigma~23 -> 17-sigma margin

typedef __attribute__((ext_vector_type(8))) short short8;
typedef __attribute__((ext_vector_type(4))) float float4v;

__device__ inline unsigned short f2bf(float f) {
    unsigned int u = __builtin_bit_cast(unsigned int, f);
    u += 0x7FFF + ((u >> 16) & 1);          // RNE
    return (unsigned short)(u >> 16);
}
__device__ inline float bf2f_lo(unsigned int u) {
    return __builtin_bit_cast(float, u << 16);
}
__device__ inline float bf2f_hi(unsigned int u) {
    return __builtin_bit_cast(float, u & 0xFFFF0000u);
}

// ---------------- merged prep: cvt x->bf16 | bucket-build | pack weights ----------------
// blocks [0,6250): cvt. [6250,7032): bucket append (4 edges/thread). [7032,7064): pack.
__global__ __launch_bounds__(256) void prep(const float* __restrict__ x,
                                            const int* __restrict__ src,
                                            const int* __restrict__ dst,
                                            const float* __restrict__ W1l,
                                            const float* __restrict__ W1r,
                                            const float* __restrict__ W2l,
                                            const float* __restrict__ W2r,
                                            unsigned short* __restrict__ xb,
                                            int* __restrict__ bcnt,
                                            unsigned int* __restrict__ bbuf,
                                            unsigned short* __restrict__ P1,
                                            unsigned short* __restrict__ P2) {
    int blk = blockIdx.x;
    if (blk < 6250) {
        int i = blk * 256 + threadIdx.x;                 // one float4 per thread
        float4 v = ((const float4*)x)[i];
        unsigned int p0 = (unsigned int)f2bf(v.x) | ((unsigned int)f2bf(v.y) << 16);
        unsigned int p1 = (unsigned int)f2bf(v.z) | ((unsigned int)f2bf(v.w) << 16);
        ((uint2*)xb)[i] = make_uint2(p0, p1);
    } else if (blk < 7032) {
        int i = (blk - 6250) * 256 + threadIdx.x;        // 4 edges per thread
        if (i < N_EDGES / 4) {
            int4 s4 = ((const int4*)src)[i];
            int4 d4 = ((const int4*)dst)[i];
            int dv[4] = {d4.x, d4.y, d4.z, d4.w};
            int sv[4] = {s4.x, s4.y, s4.z, s4.w};
            #pragma unroll
            for (int u = 0; u < 4; ++u) {
                int b = dv[u] >> 5;
                int pos = atomicAdd(&bcnt[b], 1);
                if (pos < BCAP)
                    bbuf[(size_t)b * BCAP + pos] =
                        ((unsigned int)(dv[u] & 31) << 16) | (unsigned int)sv[u];
            }
        }
    } else {
        int pblk = blk - 7032;                            // 0..31
        int t = (pblk & 15) * 256 + threadIdx.x;          // 0..4095
        int lane = t & 63;
        int ct = (t >> 6) & 7;
        int ks = t >> 9;                                  // 0..7
        const float* Wl = (pblk < 16) ? W1l : W2l;
        const float* Wr = (pblk < 16) ? W1r : W2r;
        unsigned short* P = (pblk < 16) ? P1 : P2;
        int col = ct * 16 + (lane & 15);
        int kbase = (ks & 3) * 32 + (lane >> 4) * 8;
        const float* W = (ks < 4) ? Wl : Wr;
        unsigned short* dp = P + (size_t)t * 8;
        #pragma unroll
        for (int j = 0; j < 8; ++j) dp[j] = f2bf(W[col * F + kbase + j]);
    }
}

// ---------------- bucket aggregate: one block per 32-dst bucket, LDS fp32 accumulate ----------------
// LDS layout: feature f of local row r lives at facc[r*128 + (f&1)*64 + (f>>1)]
// -> lane's two adds hit banks lane&31 (2-way across 64 lanes = free).
__global__ __launch_bounds__(256) void aggregateB(const unsigned short* __restrict__ X,
                                                  const int* __restrict__ bcnt,
                                                  const unsigned int* __restrict__ bbuf,
                                                  unsigned short* __restrict__ agg) {
    __shared__ float facc[32 * 128];     // 16 KB
    __shared__ int sdeg[32];
    int tid = threadIdx.x;
    int b = blockIdx.x;

    #pragma unroll
    for (int i = 0; i < 16; ++i) facc[tid + i * 256] = 0.f;
    if (tid < 32) sdeg[tid] = 0;
    __syncthreads();

    int total = bcnt[b];
    if (total > BCAP) total = BCAP;
    int wave = tid >> 6, lane = tid & 63;
    int per = (total + 3) >> 2;
    int s0 = wave * per;
    int s1 = s0 + per; if (s1 > total) s1 = total;
    const unsigned int* eb = bbuf + (size_t)b * BCAP;

    for (int base = s0; base < s1; base += 64) {
        int rem = s1 - base; if (rem > 64) rem = 64;
        unsigned int rec = 0;
        if (lane < rem) {
            rec = eb[base + lane];
            atomicAdd(&sdeg[rec >> 16], 1);              // each edge counted once
        }
        for (int j = 0; j < rem; j += 4) {
            unsigned int rr[4], xv[4];
            #pragma unroll
            for (int u = 0; u < 4; ++u) rr[u] = __shfl(rec, j + u);
            #pragma unroll
            for (int u = 0; u < 4; ++u)
                if (j + u < rem)
                    xv[u] = *(const unsigned int*)(X + (size_t)(rr[u] & 0xFFFFu) * F + lane * 2);
            #pragma unroll
            for (int u = 0; u < 4; ++u)
                if (j + u < rem) {
                    int dl = rr[u] >> 16;
                    atomicAdd(&facc[dl * 128 + lane],      bf2f_lo(xv[u]));
                    atomicAdd(&facc[dl * 128 + 64 + lane], bf2f_hi(xv[u]));
                }
        }
    }
    __syncthreads();

    // epilogue: row r = tid>>3, features [(tid&7)*16 .. +16)
    int r = tid >> 3;
    int node = b * 32 + r;
    if (node < N_NODES) {
        int dg = sdeg[r];
        float invd = 1.0f / (float)(dg > 0 ? dg : 1);
        int f0 = (tid & 7) * 16;
        unsigned int ow[8];
        #pragma unroll
        for (int q = 0; q < 8; ++q) {
            int fh = (f0 >> 1) + q;                      // (f0+2q)>>1
            float lo = facc[r * 128 + fh] * invd;
            float hi = facc[r * 128 + 64 + fh] * invd;
            ow[q] = (unsigned int)f2bf(lo) | ((unsigned int)f2bf(hi) << 16);
        }
        uint4* dp = (uint4*)(agg + (size_t)node * F + f0);
        dp[0] = make_uint4(ow[0], ow[1], ow[2], ow[3]);
        dp[1] = make_uint4(ow[4], ow[5], ow[6], ow[7]);
    }
}

// ---------------- fused SAGE layer: relu([A|B] @ Wcat + bias), MFMA, no LDS ----------------
// mode 0: write bf16 Hout.  mode 1: fused classifier head + log_softmax -> out (fp32).
__global__ __launch_bounds__(256) void sage_gemm(const unsigned short* __restrict__ Abf,
                                                 const unsigned short* __restrict__ Bbf,
                                                 const unsigned short* __restrict__ Pw,
                                                 const float* __restrict__ bias,
                                                 unsigned short* __restrict__ Hout,
                                                 const float* __restrict__ Wlin,
                                                 const float* __restrict__ blin,
                                                 float* __restrict__ out, int mode) {
    int lane = threadIdx.x & 63;
    int wave = threadIdx.x >> 6;
    int r0 = blockIdx.x * 64 + wave * 16;
    int rowA = r0 + (lane & 15);
    if (rowA >= N_NODES) rowA = N_NODES - 1;        // clamp; writes are guarded
    int kg = lane >> 4;                             // k-group 0..3

    short8 af[4], bfr[4];
    const short8* Ap = (const short8*)(Abf + (size_t)rowA * F);
    const short8* Bp = (const short8*)(Bbf + (size_t)rowA * F);
    #pragma unroll
    for (int ks = 0; ks < 4; ++ks) {
        af[ks]  = Ap[ks * 4 + kg];
        bfr[ks] = Bp[ks * 4 + kg];
    }

    const short8* Wp = (const short8*)Pw;
    float4v acc[8];
    #pragma unroll
    for (int ct = 0; ct < 8; ++ct) {
        float4v c = {0.f, 0.f, 0.f, 0.f};
        #pragma unroll
        for (int ks = 0; ks < 4; ++ks)
            c = __builtin_amdgcn_mfma_f32_16x16x32_bf16(af[ks], Wp[(ks * 8 + ct) * 64 + lane], c, 0, 0, 0);
        #pragma unroll
        for (int ks = 0; ks < 4; ++ks)
            c = __builtin_amdgcn_mfma_f32_16x16x32_bf16(bfr[ks], Wp[((ks + 4) * 8 + ct) * 64 + lane], c, 0, 0, 0);
        acc[ct] = c;
    }

    int colb = lane & 15;
    int rq = lane >> 4;
    #pragma unroll
    for (int ct = 0; ct < 8; ++ct) {
        float bv = bias[ct * 16 + colb];
        #pragma unroll
        for (int i = 0; i < 4; ++i)
            acc[ct][i] = fmaxf(acc[ct][i] + bv, 0.f);
    }

    if (mode == 0) {
        #pragma unroll
        for (int ct = 0; ct < 8; ++ct) {
            #pragma unroll
            for (int i = 0; i < 4; ++i) {
                int row = r0 + rq * 4 + i;
                if (row < N_NODES)
                    Hout[(size_t)row * F + ct * 16 + colb] = f2bf(acc[ct][i]);
            }
        }
    } else {
        float w0[8], w1[8];
        #pragma unroll
        for (int ct = 0; ct < 8; ++ct) {
            w0[ct] = Wlin[ct * 16 + colb];
            w1[ct] = Wlin[F + ct * 16 + colb];
        }
        #pragma unroll
        for (int i = 0; i < 4; ++i) {
            float p0 = 0.f, p1 = 0.f;
            #pragma unroll
            for (int ct = 0; ct < 8; ++ct) {
                p0 += acc[ct][i] * w0[ct];
                p1 += acc[ct][i] * w1[ct];
            }
            #pragma unroll
            for (int off = 1; off < 16; off <<= 1) {
                p0 += __shfl_xor(p0, off);
                p1 += __shfl_xor(p1, off);
            }
            int row = r0 + rq * 4 + i;
            if (colb == 0 && row < N_NODES) {
                float a = p0 + blin[0];
                float b = p1 + blin[1];
                float m = fmaxf(a, b);
                float lse = m + logf(expf(a - m) + expf(b - m));
                out[(size_t)row * 2 + 0] = a - lse;
                out[(size_t)row * 2 + 1] = b - lse;
            }
        }
    }
}

extern "C" void kernel_launch(void* const* d_in, const int* in_sizes, int n_in,
                              void* d_out, int out_size, void* d_ws, size_t ws_size,
                              hipStream_t stream) {
    const float* x    = (const float*)d_in[0];
    const int*   ei   = (const int*)d_in[1];     // [2][N_EDGES] int32
    const float* W1l  = (const float*)d_in[2];
    const float* b1l  = (const float*)d_in[3];
    const float* W1r  = (const float*)d_in[4];
    const float* W2l  = (const float*)d_in[5];
    const float* b2l  = (const float*)d_in[6];
    const float* W2r  = (const float*)d_in[7];
    const float* Wlin = (const float*)d_in[8];
    const float* blin = (const float*)d_in[9];
    float* out = (float*)d_out;

    const int* src = ei;
    const int* dst = ei + N_EDGES;

    char* ws = (char*)d_ws;
    int*            bcnt = (int*)ws;                              // 8 KB region
    unsigned int*   bbuf = (unsigned int*)(ws + 8192);            // 1563*896*4 = 5.6 MB
    unsigned short* xb   = (unsigned short*)(ws + 5767168);       // 12.8 MB
    unsigned short* h1b  = (unsigned short*)(ws + 18874368);      // 12.8 MB
    unsigned short* aggb = (unsigned short*)(ws + 32505856);      // 12.8 MB
    unsigned short* P1   = (unsigned short*)(ws + 45613056);      // 64 KB
    unsigned short* P2   = (unsigned short*)(ws + 45678592);      // 64 KB

    hipMemsetAsync(bcnt, 0, NBUCKETS * sizeof(int), stream);

    prep<<<7064, 256, 0, stream>>>(x, src, dst, W1l, W1r, W2l, W2r,
                                   xb, bcnt, bbuf, P1, P2);

    // layer 1
    aggregateB<<<NBUCKETS, 256, 0, stream>>>(xb, bcnt, bbuf, aggb);
    sage_gemm<<<782, 256, 0, stream>>>(aggb, xb, P1, b1l, h1b, nullptr, nullptr, nullptr, 0);

    // layer 2 + fused head
    aggregateB<<<NBUCKETS, 256, 0, stream>>>(h1b, bcnt, bbuf, aggb);
    sage_gemm<<<782, 256, 0, stream>>>(aggb, h1b, P2, b2l, nullptr, Wlin, blin, out, 1);
}

// Round 6
// 149.707 us; speedup vs baseline: 9.2928x; 9.2928x over previous
//
#include <hip/hip_runtime.h>
#include <math.h>

#define N_NODES 50000
#define N_EDGES 800000
#define F 128
#define ELL_CAP 64           // Poisson(16) tail: P(deg>=64) ~ e^-125 per node

typedef __attribute__((ext_vector_type(8))) short short8;
typedef __attribute__((ext_vector_type(4))) float float4v;

__device__ inline unsigned short f2bf(float f) {
    unsigned int u = __builtin_bit_cast(unsigned int, f);
    u += 0x7FFF + ((u >> 16) & 1);          // RNE
    return (unsigned short)(u >> 16);
}
__device__ inline float bf2f_lo(unsigned int u) {
    return __builtin_bit_cast(float, u << 16);
}
__device__ inline float bf2f_hi(unsigned int u) {
    return __builtin_bit_cast(float, u & 0xFFFF0000u);
}

// ---------------- merged prep: cvt x->bf16 | ELL-build (ushort) | pack weights ----------------
// blocks [0,6250): cvt. [6250,7032): ELL append, 4 edges/thread. [7032,7064): pack.
__global__ __launch_bounds__(256) void prep(const float* __restrict__ x,
                                            const int* __restrict__ src,
                                            const int* __restrict__ dst,
                                            const float* __restrict__ W1l,
                                            const float* __restrict__ W1r,
                                            const float* __restrict__ W2l,
                                            const float* __restrict__ W2r,
                                            unsigned short* __restrict__ xb,
                                            int* __restrict__ cnt,
                                            unsigned short* __restrict__ nbr,
                                            unsigned short* __restrict__ P1,
                                            unsigned short* __restrict__ P2) {
    int blk = blockIdx.x;
    if (blk < 6250) {
        int i = blk * 256 + threadIdx.x;                 // one float4 per thread
        float4 v = ((const float4*)x)[i];
        unsigned int p0 = (unsigned int)f2bf(v.x) | ((unsigned int)f2bf(v.y) << 16);
        unsigned int p1 = (unsigned int)f2bf(v.z) | ((unsigned int)f2bf(v.w) << 16);
        ((uint2*)xb)[i] = make_uint2(p0, p1);
    } else if (blk < 7032) {
        int i = (blk - 6250) * 256 + threadIdx.x;        // 4 edges per thread
        if (i < N_EDGES / 4) {
            int4 s4 = ((const int4*)src)[i];
            int4 d4 = ((const int4*)dst)[i];
            int dv[4] = {d4.x, d4.y, d4.z, d4.w};
            int sv[4] = {s4.x, s4.y, s4.z, s4.w};
            #pragma unroll
            for (int u = 0; u < 4; ++u) {
                int pos = atomicAdd(&cnt[dv[u]], 1);
                if (pos < ELL_CAP)
                    nbr[dv[u] * ELL_CAP + pos] = (unsigned short)sv[u];
            }
        }
    } else {
        int pblk = blk - 7032;                            // 0..31
        int t = (pblk & 15) * 256 + threadIdx.x;          // 0..4095
        int lane = t & 63;
        int ct = (t >> 6) & 7;
        int ks = t >> 9;                                  // 0..7
        const float* Wl = (pblk < 16) ? W1l : W2l;
        const float* Wr = (pblk < 16) ? W1r : W2r;
        unsigned short* P = (pblk < 16) ? P1 : P2;
        int col = ct * 16 + (lane & 15);
        int kbase = (ks & 3) * 32 + (lane >> 4) * 8;
        const float* W = (ks < 4) ? Wl : Wr;
        unsigned short* dp = P + (size_t)t * 8;
        #pragma unroll
        for (int j = 0; j < 8; ++j) dp[j] = f2bf(W[col * F + kbase + j]);
    }
}

// ---------------- mean aggregation: 2 nodes per wave (32 lanes each), 4-row unroll ----------------
// Per row: 32 lanes x 8B (uint2 = 4 bf16) = 256B coalesced gather. 8 gathers in flight/wave.
__global__ __launch_bounds__(256) void aggregate2(const unsigned short* __restrict__ X,
                                                  const int* __restrict__ cnt,
                                                  const unsigned short* __restrict__ nbr,
                                                  unsigned short* __restrict__ agg) {
    int tid = threadIdx.x;
    int wave = tid >> 6;
    int lane = tid & 63;
    int half = lane >> 5;            // 0/1: which node of the pair
    int hl = lane & 31;              // lane within half-wave
    int node = blockIdx.x * 8 + wave * 2 + half;   // 6250*8 = 50000 exact

    int degt = cnt[node];
    int deg = degt < ELL_CAP ? degt : ELL_CAP;
    const unsigned short* nb = nbr + node * ELL_CAP;

    float a0 = 0.f, a1 = 0.f, a2 = 0.f, a3 = 0.f;
    int s = 0;
    for (; s + 4 <= deg; s += 4) {
        ushort4 nv = *(const ushort4*)(nb + s);        // uniform per half-wave
        uint2 g0 = *(const uint2*)(X + (size_t)nv.x * F + hl * 4);
        uint2 g1 = *(const uint2*)(X + (size_t)nv.y * F + hl * 4);
        uint2 g2 = *(const uint2*)(X + (size_t)nv.z * F + hl * 4);
        uint2 g3 = *(const uint2*)(X + (size_t)nv.w * F + hl * 4);
        a0 += bf2f_lo(g0.x) + bf2f_lo(g1.x) + bf2f_lo(g2.x) + bf2f_lo(g3.x);
        a1 += bf2f_hi(g0.x) + bf2f_hi(g1.x) + bf2f_hi(g2.x) + bf2f_hi(g3.x);
        a2 += bf2f_lo(g0.y) + bf2f_lo(g1.y) + bf2f_lo(g2.y) + bf2f_lo(g3.y);
        a3 += bf2f_hi(g0.y) + bf2f_hi(g1.y) + bf2f_hi(g2.y) + bf2f_hi(g3.y);
    }
    for (; s < deg; ++s) {
        int v = nb[s];
        uint2 g = *(const uint2*)(X + (size_t)v * F + hl * 4);
        a0 += bf2f_lo(g.x); a1 += bf2f_hi(g.x);
        a2 += bf2f_lo(g.y); a3 += bf2f_hi(g.y);
    }
    float inv = 1.0f / (float)(degt > 0 ? degt : 1);
    unsigned int p0 = (unsigned int)f2bf(a0 * inv) | ((unsigned int)f2bf(a1 * inv) << 16);
    unsigned int p1 = (unsigned int)f2bf(a2 * inv) | ((unsigned int)f2bf(a3 * inv) << 16);
    *(uint2*)(agg + (size_t)node * F + hl * 4) = make_uint2(p0, p1);
}

// ---------------- fused SAGE layer: relu([A|B] @ Wcat + bias), MFMA, no LDS ----------------
// mode 0: write bf16 Hout.  mode 1: fused classifier head + log_softmax -> out (fp32).
__global__ __launch_bounds__(256) void sage_gemm(const unsigned short* __restrict__ Abf,
                                                 const unsigned short* __restrict__ Bbf,
                                                 const unsigned short* __restrict__ Pw,
                                                 const float* __restrict__ bias,
                                                 unsigned short* __restrict__ Hout,
                                                 const float* __restrict__ Wlin,
                                                 const float* __restrict__ blin,
                                                 float* __restrict__ out, int mode) {
    int lane = threadIdx.x & 63;
    int wave = threadIdx.x >> 6;
    int r0 = blockIdx.x * 64 + wave * 16;
    int rowA = r0 + (lane & 15);
    if (rowA >= N_NODES) rowA = N_NODES - 1;        // clamp; writes are guarded
    int kg = lane >> 4;                             // k-group 0..3

    short8 af[4], bfr[4];
    const short8* Ap = (const short8*)(Abf + (size_t)rowA * F);
    const short8* Bp = (const short8*)(Bbf + (size_t)rowA * F);
    #pragma unroll
    for (int ks = 0; ks < 4; ++ks) {
        af[ks]  = Ap[ks * 4 + kg];
        bfr[ks] = Bp[ks * 4 + kg];
    }

    const short8* Wp = (const short8*)Pw;
    float4v acc[8];
    #pragma unroll
    for (int ct = 0; ct < 8; ++ct) {
        float4v c = {0.f, 0.f, 0.f, 0.f};
        #pragma unroll
        for (int ks = 0; ks < 4; ++ks)
            c = __builtin_amdgcn_mfma_f32_16x16x32_bf16(af[ks], Wp[(ks * 8 + ct) * 64 + lane], c, 0, 0, 0);
        #pragma unroll
        for (int ks = 0; ks < 4; ++ks)
            c = __builtin_amdgcn_mfma_f32_16x16x32_bf16(bfr[ks], Wp[((ks + 4) * 8 + ct) * 64 + lane], c, 0, 0, 0);
        acc[ct] = c;
    }

    int colb = lane & 15;
    int rq = lane >> 4;
    #pragma unroll
    for (int ct = 0; ct < 8; ++ct) {
        float bv = bias[ct * 16 + colb];
        #pragma unroll
        for (int i = 0; i < 4; ++i)
            acc[ct][i] = fmaxf(acc[ct][i] + bv, 0.f);
    }

    if (mode == 0) {
        #pragma unroll
        for (int ct = 0; ct < 8; ++ct) {
            #pragma unroll
            for (int i = 0; i < 4; ++i) {
                int row = r0 + rq * 4 + i;
                if (row < N_NODES)
                    Hout[(size_t)row * F + ct * 16 + colb] = f2bf(acc[ct][i]);
            }
        }
    } else {
        float w0[8], w1[8];
        #pragma unroll
        for (int ct = 0; ct < 8; ++ct) {
            w0[ct] = Wlin[ct * 16 + colb];
            w1[ct] = Wlin[F + ct * 16 + colb];
        }
        #pragma unroll
        for (int i = 0; i < 4; ++i) {
            float p0 = 0.f, p1 = 0.f;
            #pragma unroll
            for (int ct = 0; ct < 8; ++ct) {
                p0 += acc[ct][i] * w0[ct];
                p1 += acc[ct][i] * w1[ct];
            }
            #pragma unroll
            for (int off = 1; off < 16; off <<= 1) {
                p0 += __shfl_xor(p0, off);
                p1 += __shfl_xor(p1, off);
            }
            int row = r0 + rq * 4 + i;
            if (colb == 0 && row < N_NODES) {
                float a = p0 + blin[0];
                float b = p1 + blin[1];
                float m = fmaxf(a, b);
                float lse = m + logf(expf(a - m) + expf(b - m));
                out[(size_t)row * 2 + 0] = a - lse;
                out[(size_t)row * 2 + 1] = b - lse;
            }
        }
    }
}

extern "C" void kernel_launch(void* const* d_in, const int* in_sizes, int n_in,
                              void* d_out, int out_size, void* d_ws, size_t ws_size,
                              hipStream_t stream) {
    const float* x    = (const float*)d_in[0];
    const int*   ei   = (const int*)d_in[1];     // [2][N_EDGES] int32
    const float* W1l  = (const float*)d_in[2];
    const float* b1l  = (const float*)d_in[3];
    const float* W1r  = (const float*)d_in[4];
    const float* W2l  = (const float*)d_in[5];
    const float* b2l  = (const float*)d_in[6];
    const float* W2r  = (const float*)d_in[7];
    const float* Wlin = (const float*)d_in[8];
    const float* blin = (const float*)d_in[9];
    float* out = (float*)d_out;

    const int* src = ei;
    const int* dst = ei + N_EDGES;

    char* ws = (char*)d_ws;
    int*            cnt  = (int*)ws;                              // 200 KB region
    unsigned short* nbr  = (unsigned short*)(ws + 262144);        // 50000*64*2 = 6.4 MB
    unsigned short* xb   = (unsigned short*)(ws + 6815744);       // 12.8 MB
    unsigned short* h1b  = (unsigned short*)(ws + 19922944);      // 12.8 MB
    unsigned short* aggb = (unsigned short*)(ws + 33030144);      // 12.8 MB
    unsigned short* P1   = (unsigned short*)(ws + 46137344);      // 64 KB
    unsigned short* P2   = (unsigned short*)(ws + 46202880);      // 64 KB

    hipMemsetAsync(cnt, 0, N_NODES * sizeof(int), stream);

    prep<<<7064, 256, 0, stream>>>(x, src, dst, W1l, W1r, W2l, W2r,
                                   xb, cnt, nbr, P1, P2);

    // layer 1
    aggregate2<<<6250, 256, 0, stream>>>(xb, cnt, nbr, aggb);
    sage_gemm<<<782, 256, 0, stream>>>(aggb, xb, P1, b1l, h1b, nullptr, nullptr, nullptr, 0);

    // layer 2 + fused head
    aggregate2<<<6250, 256, 0, stream>>>(h1b, cnt, nbr, aggb);
    sage_gemm<<<782, 256, 0, stream>>>(aggb, h1b, P2, b2l, nullptr, Wlin, blin, out, 1);
}

// Round 7
// 143.559 us; speedup vs baseline: 9.6907x; 1.0428x over previous
//
#include <hip/hip_runtime.h>
#include <math.h>

#define N_NODES 50000
#define N_EDGES 800000
#define F 128
#define ELL_CAP 64           // Poisson(16) tail: P(deg>=64) ~ e^-125 per node
#define NSHARD 8
#define RANKS 128            // edge-chunks per shard
#define EPR (N_EDGES / RANKS)           // 6250 edges per rank
#define NPS (N_NODES / NSHARD)          // 6250 nodes per shard
#define EDGE_BLKS (NSHARD * RANKS)      // 1024
#define CVT_BLKS 6250

typedef __attribute__((ext_vector_type(8))) short short8;
typedef __attribute__((ext_vector_type(4))) float float4v;

__device__ inline unsigned short f2bf(float f) {
    unsigned int u = __builtin_bit_cast(unsigned int, f);
    u += 0x7FFF + ((u >> 16) & 1);          // RNE
    return (unsigned short)(u >> 16);
}
__device__ inline float bf2f_lo(unsigned int u) {
    return __builtin_bit_cast(float, u << 16);
}
__device__ inline float bf2f_hi(unsigned int u) {
    return __builtin_bit_cast(float, u & 0xFFFF0000u);
}

// ---------------- merged prep: ELL-build (XCD-sharded) | cvt x->bf16 | pack weights ----------------
// blocks [0,1024): sharded ELL append. [1024,7274): cvt. [7274,7306): pack.
// Edge blocks FIRST so their atomic latency overlaps the cvt streaming blocks.
// Shard s commits only dst in [s*6250,(s+1)*6250) -> with blockIdx%8 -> XCD round-robin,
// each node's ELL lines are written by ONE XCD's L2 => dirty lines combine before eviction.
__global__ __launch_bounds__(256) void prep(const float* __restrict__ x,
                                            const int* __restrict__ src,
                                            const int* __restrict__ dst,
                                            const float* __restrict__ W1l,
                                            const float* __restrict__ W1r,
                                            const float* __restrict__ W2l,
                                            const float* __restrict__ W2r,
                                            unsigned short* __restrict__ xb,
                                            int* __restrict__ cnt,
                                            unsigned short* __restrict__ nbr,
                                            unsigned short* __restrict__ P1,
                                            unsigned short* __restrict__ P2) {
    int blk = blockIdx.x;
    if (blk < EDGE_BLKS) {
        int shard = blk & 7;
        int rank = blk >> 3;
        int lo = shard * NPS, hi = lo + NPS;
        int base = rank * EPR;
        for (int i = threadIdx.x; i < EPR; i += 256) {
            int d = dst[base + i];
            if (d >= lo && d < hi) {
                int s = src[base + i];
                int pos = atomicAdd(&cnt[d], 1);
                if (pos < ELL_CAP)
                    nbr[d * ELL_CAP + pos] = (unsigned short)s;
            }
        }
    } else if (blk < EDGE_BLKS + CVT_BLKS) {
        int i = (blk - EDGE_BLKS) * 256 + threadIdx.x;   // one float4 per thread
        float4 v = ((const float4*)x)[i];
        unsigned int p0 = (unsigned int)f2bf(v.x) | ((unsigned int)f2bf(v.y) << 16);
        unsigned int p1 = (unsigned int)f2bf(v.z) | ((unsigned int)f2bf(v.w) << 16);
        ((uint2*)xb)[i] = make_uint2(p0, p1);
    } else {
        int pblk = blk - (EDGE_BLKS + CVT_BLKS);          // 0..31
        int t = (pblk & 15) * 256 + threadIdx.x;          // 0..4095
        int lane = t & 63;
        int ct = (t >> 6) & 7;
        int ks = t >> 9;                                  // 0..7
        const float* Wl = (pblk < 16) ? W1l : W2l;
        const float* Wr = (pblk < 16) ? W1r : W2r;
        unsigned short* P = (pblk < 16) ? P1 : P2;
        int col = ct * 16 + (lane & 15);
        int kbase = (ks & 3) * 32 + (lane >> 4) * 8;
        const float* W = (ks < 4) ? Wl : Wr;
        unsigned short* dp = P + (size_t)t * 8;
        #pragma unroll
        for (int j = 0; j < 8; ++j) dp[j] = f2bf(W[col * F + kbase + j]);
    }
}

// ---------------- mean aggregation: 2 nodes per wave (32 lanes each), 4-row unroll ----------------
// Per row: 32 lanes x 8B (uint2 = 4 bf16) = 256B coalesced gather. 8 gathers in flight/wave.
__global__ __launch_bounds__(256) void aggregate2(const unsigned short* __restrict__ X,
                                                  const int* __restrict__ cnt,
                                                  const unsigned short* __restrict__ nbr,
                                                  unsigned short* __restrict__ agg) {
    int tid = threadIdx.x;
    int wave = tid >> 6;
    int lane = tid & 63;
    int half = lane >> 5;            // 0/1: which node of the pair
    int hl = lane & 31;              // lane within half-wave
    int node = blockIdx.x * 8 + wave * 2 + half;   // 6250*8 = 50000 exact

    int degt = cnt[node];
    int deg = degt < ELL_CAP ? degt : ELL_CAP;
    const unsigned short* nb = nbr + node * ELL_CAP;

    float a0 = 0.f, a1 = 0.f, a2 = 0.f, a3 = 0.f;
    int s = 0;
    for (; s + 4 <= deg; s += 4) {
        ushort4 nv = *(const ushort4*)(nb + s);        // uniform per half-wave
        uint2 g0 = *(const uint2*)(X + (size_t)nv.x * F + hl * 4);
        uint2 g1 = *(const uint2*)(X + (size_t)nv.y * F + hl * 4);
        uint2 g2 = *(const uint2*)(X + (size_t)nv.z * F + hl * 4);
        uint2 g3 = *(const uint2*)(X + (size_t)nv.w * F + hl * 4);
        a0 += bf2f_lo(g0.x) + bf2f_lo(g1.x) + bf2f_lo(g2.x) + bf2f_lo(g3.x);
        a1 += bf2f_hi(g0.x) + bf2f_hi(g1.x) + bf2f_hi(g2.x) + bf2f_hi(g3.x);
        a2 += bf2f_lo(g0.y) + bf2f_lo(g1.y) + bf2f_lo(g2.y) + bf2f_lo(g3.y);
        a3 += bf2f_hi(g0.y) + bf2f_hi(g1.y) + bf2f_hi(g2.y) + bf2f_hi(g3.y);
    }
    for (; s < deg; ++s) {
        int v = nb[s];
        uint2 g = *(const uint2*)(X + (size_t)v * F + hl * 4);
        a0 += bf2f_lo(g.x); a1 += bf2f_hi(g.x);
        a2 += bf2f_lo(g.y); a3 += bf2f_hi(g.y);
    }
    float inv = 1.0f / (float)(degt > 0 ? degt : 1);
    unsigned int p0 = (unsigned int)f2bf(a0 * inv) | ((unsigned int)f2bf(a1 * inv) << 16);
    unsigned int p1 = (unsigned int)f2bf(a2 * inv) | ((unsigned int)f2bf(a3 * inv) << 16);
    *(uint2*)(agg + (size_t)node * F + hl * 4) = make_uint2(p0, p1);
}

// ---------------- fused SAGE layer: relu([A|B] @ Wcat + bias), MFMA, no LDS ----------------
// mode 0: write bf16 Hout.  mode 1: fused classifier head + log_softmax -> out (fp32).
__global__ __launch_bounds__(256) void sage_gemm(const unsigned short* __restrict__ Abf,
                                                 const unsigned short* __restrict__ Bbf,
                                                 const unsigned short* __restrict__ Pw,
                                                 const float* __restrict__ bias,
                                                 unsigned short* __restrict__ Hout,
                                                 const float* __restrict__ Wlin,
                                                 const float* __restrict__ blin,
                                                 float* __restrict__ out, int mode) {
    int lane = threadIdx.x & 63;
    int wave = threadIdx.x >> 6;
    int r0 = blockIdx.x * 64 + wave * 16;
    int rowA = r0 + (lane & 15);
    if (rowA >= N_NODES) rowA = N_NODES - 1;        // clamp; writes are guarded
    int kg = lane >> 4;                             // k-group 0..3

    short8 af[4], bfr[4];
    const short8* Ap = (const short8*)(Abf + (size_t)rowA * F);
    const short8* Bp = (const short8*)(Bbf + (size_t)rowA * F);
    #pragma unroll
    for (int ks = 0; ks < 4; ++ks) {
        af[ks]  = Ap[ks * 4 + kg];
        bfr[ks] = Bp[ks * 4 + kg];
    }

    const short8* Wp = (const short8*)Pw;
    float4v acc[8];
    #pragma unroll
    for (int ct = 0; ct < 8; ++ct) {
        float4v c = {0.f, 0.f, 0.f, 0.f};
        #pragma unroll
        for (int ks = 0; ks < 4; ++ks)
            c = __builtin_amdgcn_mfma_f32_16x16x32_bf16(af[ks], Wp[(ks * 8 + ct) * 64 + lane], c, 0, 0, 0);
        #pragma unroll
        for (int ks = 0; ks < 4; ++ks)
            c = __builtin_amdgcn_mfma_f32_16x16x32_bf16(bfr[ks], Wp[((ks + 4) * 8 + ct) * 64 + lane], c, 0, 0, 0);
        acc[ct] = c;
    }

    int colb = lane & 15;
    int rq = lane >> 4;
    #pragma unroll
    for (int ct = 0; ct < 8; ++ct) {
        float bv = bias[ct * 16 + colb];
        #pragma unroll
        for (int i = 0; i < 4; ++i)
            acc[ct][i] = fmaxf(acc[ct][i] + bv, 0.f);
    }

    if (mode == 0) {
        #pragma unroll
        for (int ct = 0; ct < 8; ++ct) {
            #pragma unroll
            for (int i = 0; i < 4; ++i) {
                int row = r0 + rq * 4 + i;
                if (row < N_NODES)
                    Hout[(size_t)row * F + ct * 16 + colb] = f2bf(acc[ct][i]);
            }
        }
    } else {
        float w0[8], w1[8];
        #pragma unroll
        for (int ct = 0; ct < 8; ++ct) {
            w0[ct] = Wlin[ct * 16 + colb];
            w1[ct] = Wlin[F + ct * 16 + colb];
        }
        #pragma unroll
        for (int i = 0; i < 4; ++i) {
            float p0 = 0.f, p1 = 0.f;
            #pragma unroll
            for (int ct = 0; ct < 8; ++ct) {
                p0 += acc[ct][i] * w0[ct];
                p1 += acc[ct][i] * w1[ct];
            }
            #pragma unroll
            for (int off = 1; off < 16; off <<= 1) {
                p0 += __shfl_xor(p0, off);
                p1 += __shfl_xor(p1, off);
            }
            int row = r0 + rq * 4 + i;
            if (colb == 0 && row < N_NODES) {
                float a = p0 + blin[0];
                float b = p1 + blin[1];
                float m = fmaxf(a, b);
                float lse = m + logf(expf(a - m) + expf(b - m));
                out[(size_t)row * 2 + 0] = a - lse;
                out[(size_t)row * 2 + 1] = b - lse;
            }
        }
    }
}

extern "C" void kernel_launch(void* const* d_in, const int* in_sizes, int n_in,
                              void* d_out, int out_size, void* d_ws, size_t ws_size,
                              hipStream_t stream) {
    const float* x    = (const float*)d_in[0];
    const int*   ei   = (const int*)d_in[1];     // [2][N_EDGES] int32
    const float* W1l  = (const float*)d_in[2];
    const float* b1l  = (const float*)d_in[3];
    const float* W1r  = (const float*)d_in[4];
    const float* W2l  = (const float*)d_in[5];
    const float* b2l  = (const float*)d_in[6];
    const float* W2r  = (const float*)d_in[7];
    const float* Wlin = (const float*)d_in[8];
    const float* blin = (const float*)d_in[9];
    float* out = (float*)d_out;

    const int* src = ei;
    const int* dst = ei + N_EDGES;

    char* ws = (char*)d_ws;
    int*            cnt  = (int*)ws;                              // 200 KB region
    unsigned short* nbr  = (unsigned short*)(ws + 262144);        // 50000*64*2 = 6.4 MB
    unsigned short* xb   = (unsigned short*)(ws + 6815744);       // 12.8 MB
    unsigned short* h1b  = (unsigned short*)(ws + 19922944);      // 12.8 MB
    unsigned short* aggb = (unsigned short*)(ws + 33030144);      // 12.8 MB
    unsigned short* P1   = (unsigned short*)(ws + 46137344);      // 64 KB
    unsigned short* P2   = (unsigned short*)(ws + 46202880);      // 64 KB

    hipMemsetAsync(cnt, 0, N_NODES * sizeof(int), stream);

    prep<<<EDGE_BLKS + CVT_BLKS + 32, 256, 0, stream>>>(x, src, dst, W1l, W1r, W2l, W2r,
                                                        xb, cnt, nbr, P1, P2);

    // layer 1
    aggregate2<<<6250, 256, 0, stream>>>(xb, cnt, nbr, aggb);
    sage_gemm<<<782, 256, 0, stream>>>(aggb, xb, P1, b1l, h1b, nullptr, nullptr, nullptr, 0);

    // layer 2 + fused head
    aggregate2<<<6250, 256, 0, stream>>>(h1b, cnt, nbr, aggb);
    sage_gemm<<<782, 256, 0, stream>>>(aggb, h1b, P2, b2l, nullptr, Wlin, blin, out, 1);
}

// Round 8
// 137.883 us; speedup vs baseline: 10.0897x; 1.0412x over previous
//
#include <hip/hip_runtime.h>
#include <math.h>

#define N_NODES 50000
#define N_EDGES 800000
#define F 128
#define ELL_CAP 64           // Poisson(16) tail: P(deg>=64) ~ e^-125 per node
#define NSHARD 8
#define RANKS 128
#define EPR (N_EDGES / RANKS)           // 6250 edges per rank-chunk
#define NPS (N_NODES / NSHARD)          // 6250 nodes per shard
#define NBPS 25                         // buckets per shard (256 nodes each)
#define NBUCK (NSHARD * NBPS)           // 200 buckets
#define BIN_CAP 80                      // per-block per-bin: mean 32, 8 sigma
#define BUCK_CAP 4608                   // per-bucket total: mean 4000, ~9 sigma
#define EDGE_BLKS (NSHARD * RANKS)      // 1024
#define CVT_BLKS 6250

typedef __attribute__((ext_vector_type(8))) short short8;
typedef __attribute__((ext_vector_type(4))) float float4v;

__device__ inline unsigned short f2bf(float f) {
    unsigned int u = __builtin_bit_cast(unsigned int, f);
    u += 0x7FFF + ((u >> 16) & 1);          // RNE
    return (unsigned short)(u >> 16);
}
__device__ inline float bf2f_lo(unsigned int u) {
    return __builtin_bit_cast(float, u << 16);
}
__device__ inline float bf2f_hi(unsigned int u) {
    return __builtin_bit_cast(float, u & 0xFFFF0000u);
}

// ---------------- prep1: edge partition (LDS bins + reserved runs) | cvt | pack ----------------
// blocks [0,1024): shard s=blk&7, rank r=blk>>3. Bin shard-matching edges of chunk r
// into 25 LDS bins (256 nodes each), then flush each bin as ONE contiguous run
// (1 atomic reservation + burst copy) -> dirty lines combine, no per-edge scatter.
__global__ __launch_bounds__(256) void prep1(const float* __restrict__ x,
                                             const int* __restrict__ src,
                                             const int* __restrict__ dst,
                                             const float* __restrict__ W1l,
                                             const float* __restrict__ W1r,
                                             const float* __restrict__ W2l,
                                             const float* __restrict__ W2r,
                                             unsigned short* __restrict__ xb,
                                             int* __restrict__ tails,
                                             unsigned int* __restrict__ bucketEdges,
                                             unsigned short* __restrict__ P1,
                                             unsigned short* __restrict__ P2) {
    int blk = blockIdx.x;
    int tid = threadIdx.x;
    if (blk < EDGE_BLKS) {
        __shared__ int bin_cnt[NBPS];
        __shared__ int bin_base[NBPS];
        __shared__ unsigned int bins[NBPS * BIN_CAP];     // 8 KB
        int shard = blk & 7;
        int rank = blk >> 3;
        int lo = shard * NPS;
        if (tid < NBPS) bin_cnt[tid] = 0;
        __syncthreads();
        int base = rank * EPR;
        for (int i = tid; i < EPR; i += 256) {
            int d = dst[base + i];
            unsigned int du = (unsigned int)(d - lo);
            if (du < (unsigned int)NPS) {
                int s = src[base + i];
                int lb = du >> 8;                          // 0..24
                int pos = atomicAdd(&bin_cnt[lb], 1);
                if (pos < BIN_CAP)
                    bins[lb * BIN_CAP + pos] = ((du & 255u) << 16) | (unsigned int)s;
            }
        }
        __syncthreads();
        if (tid < NBPS) {
            int c = bin_cnt[tid]; if (c > BIN_CAP) c = BIN_CAP;
            bin_cnt[tid] = c;
            bin_base[tid] = atomicAdd(&tails[shard * NBPS + tid], c);
        }
        __syncthreads();
        for (int b2 = 0; b2 < NBPS; ++b2) {
            int c = bin_cnt[b2];
            int rb = bin_base[b2];
            unsigned int* dp = bucketEdges + (size_t)(shard * NBPS + b2) * BUCK_CAP;
            for (int i = tid; i < c; i += 256)
                if (rb + i < BUCK_CAP) dp[rb + i] = bins[b2 * BIN_CAP + i];
        }
    } else if (blk < EDGE_BLKS + CVT_BLKS) {
        int i = (blk - EDGE_BLKS) * 256 + tid;            // one float4 per thread
        float4 v = ((const float4*)x)[i];
        unsigned int p0 = (unsigned int)f2bf(v.x) | ((unsigned int)f2bf(v.y) << 16);
        unsigned int p1 = (unsigned int)f2bf(v.z) | ((unsigned int)f2bf(v.w) << 16);
        ((uint2*)xb)[i] = make_uint2(p0, p1);
    } else {
        int pblk = blk - (EDGE_BLKS + CVT_BLKS);          // 0..31
        int t = (pblk & 15) * 256 + tid;                  // 0..4095
        int lane = t & 63;
        int ct = (t >> 6) & 7;
        int ks = t >> 9;                                  // 0..7
        const float* Wl = (pblk < 16) ? W1l : W2l;
        const float* Wr = (pblk < 16) ? W1r : W2r;
        unsigned short* P = (pblk < 16) ? P1 : P2;
        int col = ct * 16 + (lane & 15);
        int kbase = (ks & 3) * 32 + (lane >> 4) * 8;
        const float* W = (ks < 4) ? Wl : Wr;
        unsigned short* dp = P + (size_t)t * 8;
        #pragma unroll
        for (int j = 0; j < 8; ++j) dp[j] = f2bf(W[col * F + kbase + j]);
    }
}

// ---------------- prep2: per-bucket ELL build in LDS, dense streamed output ----------------
__global__ __launch_bounds__(256) void ell_build(const int* __restrict__ tails,
                                                 const unsigned int* __restrict__ bucketEdges,
                                                 int* __restrict__ cnt,
                                                 unsigned short* __restrict__ nbr) {
    __shared__ int cl[256];
    __shared__ unsigned short ell[256 * ELL_CAP];         // 32 KB
    int b = blockIdx.x;                                   // 0..199
    int tid = threadIdx.x;
    cl[tid] = 0;
    __syncthreads();
    int T = tails[b]; if (T > BUCK_CAP) T = BUCK_CAP;
    const unsigned int* eb = bucketEdges + (size_t)b * BUCK_CAP;
    for (int i = tid; i < T; i += 256) {
        unsigned int rec = eb[i];
        int nib = rec >> 16;
        int pos = atomicAdd(&cl[nib], 1);
        if (pos < ELL_CAP) ell[nib * ELL_CAP + pos] = (unsigned short)(rec & 0xFFFFu);
    }
    __syncthreads();
    int shard = b / NBPS, lb = b % NBPS;
    int nb0 = shard * NPS + lb * 256;
    int nn = NPS - lb * 256; if (nn > 256) nn = 256;      // 256 or 106
    if (tid < nn) cnt[nb0 + tid] = cl[tid];
    // stream ELL slab (garbage beyond per-row count is never read downstream)
    const uint4* s4 = (const uint4*)ell;
    uint4* d4 = (uint4*)(nbr + (size_t)nb0 * ELL_CAP);
    int n4 = nn * (ELL_CAP * 2 / 16);                     // nn * 8 uint4s
    for (int i = tid; i < n4; i += 256) d4[i] = s4[i];
}

// ---------------- mean aggregation: 2 nodes per wave (32 lanes each), 4-row unroll ----------------
__global__ __launch_bounds__(256) void aggregate2(const unsigned short* __restrict__ X,
                                                  const int* __restrict__ cnt,
                                                  const unsigned short* __restrict__ nbr,
                                                  unsigned short* __restrict__ agg) {
    int tid = threadIdx.x;
    int wave = tid >> 6;
    int lane = tid & 63;
    int half = lane >> 5;
    int hl = lane & 31;
    int node = blockIdx.x * 8 + wave * 2 + half;   // 6250*8 = 50000 exact

    int degt = cnt[node];
    int deg = degt < ELL_CAP ? degt : ELL_CAP;
    const unsigned short* nb = nbr + node * ELL_CAP;

    float a0 = 0.f, a1 = 0.f, a2 = 0.f, a3 = 0.f;
    int s = 0;
    for (; s + 4 <= deg; s += 4) {
        ushort4 nv = *(const ushort4*)(nb + s);
        uint2 g0 = *(const uint2*)(X + (size_t)nv.x * F + hl * 4);
        uint2 g1 = *(const uint2*)(X + (size_t)nv.y * F + hl * 4);
        uint2 g2 = *(const uint2*)(X + (size_t)nv.z * F + hl * 4);
        uint2 g3 = *(const uint2*)(X + (size_t)nv.w * F + hl * 4);
        a0 += bf2f_lo(g0.x) + bf2f_lo(g1.x) + bf2f_lo(g2.x) + bf2f_lo(g3.x);
        a1 += bf2f_hi(g0.x) + bf2f_hi(g1.x) + bf2f_hi(g2.x) + bf2f_hi(g3.x);
        a2 += bf2f_lo(g0.y) + bf2f_lo(g1.y) + bf2f_lo(g2.y) + bf2f_lo(g3.y);
        a3 += bf2f_hi(g0.y) + bf2f_hi(g1.y) + bf2f_hi(g2.y) + bf2f_hi(g3.y);
    }
    for (; s < deg; ++s) {
        int v = nb[s];
        uint2 g = *(const uint2*)(X + (size_t)v * F + hl * 4);
        a0 += bf2f_lo(g.x); a1 += bf2f_hi(g.x);
        a2 += bf2f_lo(g.y); a3 += bf2f_hi(g.y);
    }
    float inv = 1.0f / (float)(degt > 0 ? degt : 1);
    unsigned int p0 = (unsigned int)f2bf(a0 * inv) | ((unsigned int)f2bf(a1 * inv) << 16);
    unsigned int p1 = (unsigned int)f2bf(a2 * inv) | ((unsigned int)f2bf(a3 * inv) << 16);
    *(uint2*)(agg + (size_t)node * F + hl * 4) = make_uint2(p0, p1);
}

// ---------------- fused SAGE layer: relu([A|B] @ Wcat + bias), MFMA, no LDS ----------------
__global__ __launch_bounds__(256) void sage_gemm(const unsigned short* __restrict__ Abf,
                                                 const unsigned short* __restrict__ Bbf,
                                                 const unsigned short* __restrict__ Pw,
                                                 const float* __restrict__ bias,
                                                 unsigned short* __restrict__ Hout,
                                                 const float* __restrict__ Wlin,
                                                 const float* __restrict__ blin,
                                                 float* __restrict__ out, int mode) {
    int lane = threadIdx.x & 63;
    int wave = threadIdx.x >> 6;
    int r0 = blockIdx.x * 64 + wave * 16;
    int rowA = r0 + (lane & 15);
    if (rowA >= N_NODES) rowA = N_NODES - 1;        // clamp; writes are guarded
    int kg = lane >> 4;

    short8 af[4], bfr[4];
    const short8* Ap = (const short8*)(Abf + (size_t)rowA * F);
    const short8* Bp = (const short8*)(Bbf + (size_t)rowA * F);
    #pragma unroll
    for (int ks = 0; ks < 4; ++ks) {
        af[ks]  = Ap[ks * 4 + kg];
        bfr[ks] = Bp[ks * 4 + kg];
    }

    const short8* Wp = (const short8*)Pw;
    float4v acc[8];
    #pragma unroll
    for (int ct = 0; ct < 8; ++ct) {
        float4v c = {0.f, 0.f, 0.f, 0.f};
        #pragma unroll
        for (int ks = 0; ks < 4; ++ks)
            c = __builtin_amdgcn_mfma_f32_16x16x32_bf16(af[ks], Wp[(ks * 8 + ct) * 64 + lane], c, 0, 0, 0);
        #pragma unroll
        for (int ks = 0; ks < 4; ++ks)
            c = __builtin_amdgcn_mfma_f32_16x16x32_bf16(bfr[ks], Wp[((ks + 4) * 8 + ct) * 64 + lane], c, 0, 0, 0);
        acc[ct] = c;
    }

    int colb = lane & 15;
    int rq = lane >> 4;
    #pragma unroll
    for (int ct = 0; ct < 8; ++ct) {
        float bv = bias[ct * 16 + colb];
        #pragma unroll
        for (int i = 0; i < 4; ++i)
            acc[ct][i] = fmaxf(acc[ct][i] + bv, 0.f);
    }

    if (mode == 0) {
        #pragma unroll
        for (int ct = 0; ct < 8; ++ct) {
            #pragma unroll
            for (int i = 0; i < 4; ++i) {
                int row = r0 + rq * 4 + i;
                if (row < N_NODES)
                    Hout[(size_t)row * F + ct * 16 + colb] = f2bf(acc[ct][i]);
            }
        }
    } else {
        float w0[8], w1[8];
        #pragma unroll
        for (int ct = 0; ct < 8; ++ct) {
            w0[ct] = Wlin[ct * 16 + colb];
            w1[ct] = Wlin[F + ct * 16 + colb];
        }
        #pragma unroll
        for (int i = 0; i < 4; ++i) {
            float p0 = 0.f, p1 = 0.f;
            #pragma unroll
            for (int ct = 0; ct < 8; ++ct) {
                p0 += acc[ct][i] * w0[ct];
                p1 += acc[ct][i] * w1[ct];
            }
            #pragma unroll
            for (int off = 1; off < 16; off <<= 1) {
                p0 += __shfl_xor(p0, off);
                p1 += __shfl_xor(p1, off);
            }
            int row = r0 + rq * 4 + i;
            if (colb == 0 && row < N_NODES) {
                float a = p0 + blin[0];
                float b = p1 + blin[1];
                float m = fmaxf(a, b);
                float lse = m + logf(expf(a - m) + expf(b - m));
                out[(size_t)row * 2 + 0] = a - lse;
                out[(size_t)row * 2 + 1] = b - lse;
            }
        }
    }
}

extern "C" void kernel_launch(void* const* d_in, const int* in_sizes, int n_in,
                              void* d_out, int out_size, void* d_ws, size_t ws_size,
                              hipStream_t stream) {
    const float* x    = (const float*)d_in[0];
    const int*   ei   = (const int*)d_in[1];     // [2][N_EDGES] int32
    const float* W1l  = (const float*)d_in[2];
    const float* b1l  = (const float*)d_in[3];
    const float* W1r  = (const float*)d_in[4];
    const float* W2l  = (const float*)d_in[5];
    const float* b2l  = (const float*)d_in[6];
    const float* W2r  = (const float*)d_in[7];
    const float* Wlin = (const float*)d_in[8];
    const float* blin = (const float*)d_in[9];
    float* out = (float*)d_out;

    const int* src = ei;
    const int* dst = ei + N_EDGES;

    char* ws = (char*)d_ws;
    int*            tails = (int*)ws;                              // 800 B (pad 4 KB)
    unsigned int*   bEdge = (unsigned int*)(ws + 4096);            // 200*4608*4 = 3,686,400
    int*            cnt   = (int*)(ws + 3694592);                  // 200,000 B
    unsigned short* nbr   = (unsigned short*)(ws + 3895296);       // 6,400,000 B
    unsigned short* xb    = (unsigned short*)(ws + 10296320);      // 12.8 MB
    unsigned short* h1b   = (unsigned short*)(ws + 23097344);      // 12.8 MB
    unsigned short* aggb  = (unsigned short*)(ws + 35898368);      // 12.8 MB
    unsigned short* P1    = (unsigned short*)(ws + 48699392);      // 64 KB
    unsigned short* P2    = (unsigned short*)(ws + 48764928);      // 64 KB

    hipMemsetAsync(tails, 0, NBUCK * sizeof(int), stream);

    prep1<<<EDGE_BLKS + CVT_BLKS + 32, 256, 0, stream>>>(x, src, dst, W1l, W1r, W2l, W2r,
                                                         xb, tails, bEdge, P1, P2);
    ell_build<<<NBUCK, 256, 0, stream>>>(tails, bEdge, cnt, nbr);

    // layer 1
    aggregate2<<<6250, 256, 0, stream>>>(xb, cnt, nbr, aggb);
    sage_gemm<<<782, 256, 0, stream>>>(aggb, xb, P1, b1l, h1b, nullptr, nullptr, nullptr, 0);

    // layer 2 + fused head
    aggregate2<<<6250, 256, 0, stream>>>(h1b, cnt, nbr, aggb);
    sage_gemm<<<782, 256, 0, stream>>>(aggb, h1b, P2, b2l, nullptr, Wlin, blin, out, 1);
}

// Round 10
// 127.611 us; speedup vs baseline: 10.9018x; 1.0805x over previous
//
#include <hip/hip_runtime.h>
#include <math.h>

#define N_NODES 50000
#define N_EDGES 800000
#define F 128
#define ELL_CAP 64           // Poisson(16) tail: P(deg>=64) ~ e^-125 per node
#define NSHARD 8
#define RANKS 128
#define EPR (N_EDGES / RANKS)           // 6250 edges per rank-chunk
#define NPS (N_NODES / NSHARD)          // 6250 nodes per shard
#define NBPS 25                         // buckets per shard (256 nodes each)
#define NBUCK (NSHARD * NBPS)           // 200 buckets
#define BIN_CAP 80                      // per-block per-bin: mean 32, 8 sigma
#define BUCK_CAP 4608                   // per-bucket total: mean 4000, ~9 sigma
#define EDGE_BLKS (NSHARD * RANKS)      // 1024
#define CVT_BLKS 6250                   // 8 rows per block

typedef __attribute__((ext_vector_type(8))) short short8;
typedef __attribute__((ext_vector_type(4))) float float4v;

__device__ inline unsigned short f2bf(float f) {
    unsigned int u = __builtin_bit_cast(unsigned int, f);
    u += 0x7FFF + ((u >> 16) & 1);          // RNE
    return (unsigned short)(u >> 16);
}
__device__ inline float bf2f_lo(unsigned int u) {
    return __builtin_bit_cast(float, u << 16);
}
__device__ inline float bf2f_hi(unsigned int u) {
    return __builtin_bit_cast(float, u & 0xFFFF0000u);
}
__device__ inline float i8f(unsigned int u, int k) {       // sign-extend byte k -> float
    return (float)((signed char)(u >> (k * 8)));
}

// ---------------- prep1: edge partition (LDS bins + reserved runs) | cvt+quant | pack ----------------
__global__ __launch_bounds__(256) void prep1(const float* __restrict__ x,
                                             const int* __restrict__ src,
                                             const int* __restrict__ dst,
                                             const float* __restrict__ W1l,
                                             const float* __restrict__ W1r,
                                             const float* __restrict__ W2l,
                                             const float* __restrict__ W2r,
                                             unsigned short* __restrict__ xb,
                                             unsigned char* __restrict__ xq,
                                             float* __restrict__ xscale,
                                             int* __restrict__ tails,
                                             unsigned int* __restrict__ bucketEdges,
                                             unsigned short* __restrict__ P1,
                                             unsigned short* __restrict__ P2) {
    int blk = blockIdx.x;
    int tid = threadIdx.x;
    if (blk < EDGE_BLKS) {
        __shared__ int bin_cnt[NBPS];
        __shared__ int bin_base[NBPS];
        __shared__ unsigned int bins[NBPS * BIN_CAP];     // 8 KB
        int shard = blk & 7;
        int rank = blk >> 3;
        int lo = shard * NPS;
        if (tid < NBPS) bin_cnt[tid] = 0;
        __syncthreads();
        int base = rank * EPR;
        for (int i = tid; i < EPR; i += 256) {
            int d = dst[base + i];
            unsigned int du = (unsigned int)(d - lo);
            if (du < (unsigned int)NPS) {
                int s = src[base + i];
                int lb = du >> 8;                          // 0..24
                int pos = atomicAdd(&bin_cnt[lb], 1);
                if (pos < BIN_CAP)
                    bins[lb * BIN_CAP + pos] = ((du & 255u) << 16) | (unsigned int)s;
            }
        }
        __syncthreads();
        if (tid < NBPS) {
            int c = bin_cnt[tid]; if (c > BIN_CAP) c = BIN_CAP;
            bin_cnt[tid] = c;
            bin_base[tid] = atomicAdd(&tails[shard * NBPS + tid], c);
        }
        __syncthreads();
        for (int b2 = 0; b2 < NBPS; ++b2) {
            int c = bin_cnt[b2];
            int rb = bin_base[b2];
            unsigned int* dp = bucketEdges + (size_t)(shard * NBPS + b2) * BUCK_CAP;
            for (int i = tid; i < c; i += 256)
                if (rb + i < BUCK_CAP) dp[rb + i] = bins[b2 * BIN_CAP + i];
        }
    } else if (blk < EDGE_BLKS + CVT_BLKS) {
        // one row per 32-lane half-wave: bf16 copy + int8 row-quant (per-row absmax)
        int row = (blk - EDGE_BLKS) * 8 + (tid >> 5);
        int hl = tid & 31;
        float4 v = ((const float4*)x)[row * 32 + hl];
        float m = fmaxf(fmaxf(fabsf(v.x), fabsf(v.y)), fmaxf(fabsf(v.z), fabsf(v.w)));
        #pragma unroll
        for (int off = 1; off < 32; off <<= 1) m = fmaxf(m, __shfl_xor(m, off));
        float inv = m > 0.f ? 127.f / m : 0.f;
        int q0 = (int)rintf(v.x * inv), q1 = (int)rintf(v.y * inv);
        int q2 = (int)rintf(v.z * inv), q3 = (int)rintf(v.w * inv);
        unsigned int qp = (q0 & 255) | ((q1 & 255) << 8) | ((q2 & 255) << 16) | ((q3 & 255) << 24);
        ((unsigned int*)xq)[row * 32 + hl] = qp;
        unsigned int p0 = (unsigned int)f2bf(v.x) | ((unsigned int)f2bf(v.y) << 16);
        unsigned int p1 = (unsigned int)f2bf(v.z) | ((unsigned int)f2bf(v.w) << 16);
        ((uint2*)xb)[row * 32 + hl] = make_uint2(p0, p1);
        if (hl == 0) xscale[row] = m * (1.f / 127.f);
    } else {
        int pblk = blk - (EDGE_BLKS + CVT_BLKS);          // 0..31
        int t = (pblk & 15) * 256 + tid;                  // 0..4095
        int lane = t & 63;
        int ct = (t >> 6) & 7;
        int ks = t >> 9;                                  // 0..7
        const float* Wl = (pblk < 16) ? W1l : W2l;
        const float* Wr = (pblk < 16) ? W1r : W2r;
        unsigned short* P = (pblk < 16) ? P1 : P2;
        int col = ct * 16 + (lane & 15);
        int kbase = (ks & 3) * 32 + (lane >> 4) * 8;
        const float* W = (ks < 4) ? Wl : Wr;
        unsigned short* dp = P + (size_t)t * 8;
        #pragma unroll
        for (int j = 0; j < 8; ++j) dp[j] = f2bf(W[col * F + kbase + j]);
    }
}

// ---------------- prep2: per-bucket ELL build in LDS, dense streamed output ----------------
__global__ __launch_bounds__(256) void ell_build(const int* __restrict__ tails,
                                                 const unsigned int* __restrict__ bucketEdges,
                                                 int* __restrict__ cnt,
                                                 unsigned short* __restrict__ nbr) {
    __shared__ int cl[256];
    __shared__ unsigned short ell[256 * ELL_CAP];         // 32 KB
    int b = blockIdx.x;                                   // 0..199
    int tid = threadIdx.x;
    cl[tid] = 0;
    __syncthreads();
    int T = tails[b]; if (T > BUCK_CAP) T = BUCK_CAP;
    const unsigned int* eb = bucketEdges + (size_t)b * BUCK_CAP;
    for (int i = tid; i < T; i += 256) {
        unsigned int rec = eb[i];
        int nib = rec >> 16;
        int pos = atomicAdd(&cl[nib], 1);
        if (pos < ELL_CAP) ell[nib * ELL_CAP + pos] = (unsigned short)(rec & 0xFFFFu);
    }
    __syncthreads();
    int shard = b / NBPS, lb = b % NBPS;
    int nb0 = shard * NPS + lb * 256;
    int nn = NPS - lb * 256; if (nn > 256) nn = 256;      // 256 or 106
    if (tid < nn) cnt[nb0 + tid] = cl[tid];
    const uint4* s4 = (const uint4*)ell;
    uint4* d4 = (uint4*)(nbr + (size_t)nb0 * ELL_CAP);
    int n4 = nn * (ELL_CAP * 2 / 16);                     // nn * 8 uint4s
    for (int i = tid; i < n4; i += 256) d4[i] = s4[i];
}

// ---------------- mean aggregation over int8-quantized rows: 2 nodes/wave, 4-row unroll ----------------
// Per row: 32 lanes x 4B (int8x4) = 128B coalesced gather + one 4B scale broadcast.
__global__ __launch_bounds__(256) void aggregate_q(const unsigned char* __restrict__ Xq,
                                                   const float* __restrict__ xs,
                                                   const int* __restrict__ cnt,
                                                   const unsigned short* __restrict__ nbr,
                                                   unsigned short* __restrict__ agg) {
    int tid = threadIdx.x;
    int wave = tid >> 6;
    int lane = tid & 63;
    int half = lane >> 5;
    int hl = lane & 31;
    int node = blockIdx.x * 8 + wave * 2 + half;   // 6250*8 = 50000 exact

    int degt = cnt[node];
    int deg = degt < ELL_CAP ? degt : ELL_CAP;
    const unsigned short* nb = nbr + node * ELL_CAP;
    const unsigned int* Xu = (const unsigned int*)Xq;

    float a0 = 0.f, a1 = 0.f, a2 = 0.f, a3 = 0.f;
    int s = 0;
    for (; s + 4 <= deg; s += 4) {
        ushort4 nv = *(const ushort4*)(nb + s);
        unsigned int g0 = Xu[nv.x * 32 + hl]; float s0 = xs[nv.x];
        unsigned int g1 = Xu[nv.y * 32 + hl]; float s1 = xs[nv.y];
        unsigned int g2 = Xu[nv.z * 32 + hl]; float s2 = xs[nv.z];
        unsigned int g3 = Xu[nv.w * 32 + hl]; float s3 = xs[nv.w];
        a0 += i8f(g0, 0) * s0 + i8f(g1, 0) * s1 + i8f(g2, 0) * s2 + i8f(g3, 0) * s3;
        a1 += i8f(g0, 1) * s0 + i8f(g1, 1) * s1 + i8f(g2, 1) * s2 + i8f(g3, 1) * s3;
        a2 += i8f(g0, 2) * s0 + i8f(g1, 2) * s1 + i8f(g2, 2) * s2 + i8f(g3, 2) * s3;
        a3 += i8f(g0, 3) * s0 + i8f(g1, 3) * s1 + i8f(g2, 3) * s2 + i8f(g3, 3) * s3;
    }
    for (; s < deg; ++s) {
        int v = nb[s];
        unsigned int g = Xu[v * 32 + hl]; float sc = xs[v];
        a0 += i8f(g, 0) * sc; a1 += i8f(g, 1) * sc;
        a2 += i8f(g, 2) * sc; a3 += i8f(g, 3) * sc;
    }
    float inv = 1.0f / (float)(degt > 0 ? degt : 1);
    unsigned int p0 = (unsigned int)f2bf(a0 * inv) | ((unsigned int)f2bf(a1 * inv) << 16);
    unsigned int p1 = (unsigned int)f2bf(a2 * inv) | ((unsigned int)f2bf(a3 * inv) << 16);
    *(uint2*)(agg + (size_t)node * F + hl * 4) = make_uint2(p0, p1);
}

// ---------------- fused SAGE layer: relu([A|B] @ Wcat + bias), MFMA, no LDS ----------------
// mode 0: write bf16 Hout + int8 Hq/Hscale.  mode 1: fused head + log_softmax -> out.
__global__ __launch_bounds__(256) void sage_gemm(const unsigned short* __restrict__ Abf,
                                                 const unsigned short* __restrict__ Bbf,
                                                 const unsigned short* __restrict__ Pw,
                                                 const float* __restrict__ bias,
                                                 unsigned short* __restrict__ Hout,
                                                 unsigned char* __restrict__ Hq,
                                                 float* __restrict__ Hscale,
                                                 const float* __restrict__ Wlin,
                                                 const float* __restrict__ blin,
                                                 float* __restrict__ out, int mode) {
    int lane = threadIdx.x & 63;
    int wave = threadIdx.x >> 6;
    int r0 = blockIdx.x * 64 + wave * 16;
    int rowA = r0 + (lane & 15);
    if (rowA >= N_NODES) rowA = N_NODES - 1;        // clamp; writes are guarded
    int kg = lane >> 4;

    short8 af[4], bfr[4];
    const short8* Ap = (const short8*)(Abf + (size_t)rowA * F);
    const short8* Bp = (const short8*)(Bbf + (size_t)rowA * F);
    #pragma unroll
    for (int ks = 0; ks < 4; ++ks) {
        af[ks]  = Ap[ks * 4 + kg];
        bfr[ks] = Bp[ks * 4 + kg];
    }

    const short8* Wp = (const short8*)Pw;
    float4v acc[8];
    #pragma unroll
    for (int ct = 0; ct < 8; ++ct) {
        float4v c = {0.f, 0.f, 0.f, 0.f};
        #pragma unroll
        for (int ks = 0; ks < 4; ++ks)
            c = __builtin_amdgcn_mfma_f32_16x16x32_bf16(af[ks], Wp[(ks * 8 + ct) * 64 + lane], c, 0, 0, 0);
        #pragma unroll
        for (int ks = 0; ks < 4; ++ks)
            c = __builtin_amdgcn_mfma_f32_16x16x32_bf16(bfr[ks], Wp[((ks + 4) * 8 + ct) * 64 + lane], c, 0, 0, 0);
        acc[ct] = c;
    }

    int colb = lane & 15;
    int rq = lane >> 4;
    #pragma unroll
    for (int ct = 0; ct < 8; ++ct) {
        float bv = bias[ct * 16 + colb];
        #pragma unroll
        for (int i = 0; i < 4; ++i)
            acc[ct][i] = fmaxf(acc[ct][i] + bv, 0.f);
    }

    if (mode == 0) {
        #pragma unroll
        for (int ct = 0; ct < 8; ++ct) {
            #pragma unroll
            for (int i = 0; i < 4; ++i) {
                int row = r0 + rq * 4 + i;
                if (row < N_NODES)
                    Hout[(size_t)row * F + ct * 16 + colb] = f2bf(acc[ct][i]);
            }
        }
        // int8 row-quant: absmax over 8 local cols, then 16-lane (colb-group) reduce
        #pragma unroll
        for (int i = 0; i < 4; ++i) {
            float m = 0.f;
            #pragma unroll
            for (int ct = 0; ct < 8; ++ct) m = fmaxf(m, acc[ct][i]);   // relu'd -> >=0
            #pragma unroll
            for (int off = 1; off < 16; off <<= 1) m = fmaxf(m, __shfl_xor(m, off));
            float inv = m > 0.f ? 127.f / m : 0.f;
            int row = r0 + rq * 4 + i;
            if (row < N_NODES) {
                if (colb == 0) Hscale[row] = m * (1.f / 127.f);
                #pragma unroll
                for (int ct = 0; ct < 8; ++ct) {
                    int q = (int)rintf(acc[ct][i] * inv);
                    Hq[(size_t)row * F + ct * 16 + colb] = (unsigned char)q;
                }
            }
        }
    } else {
        float w0[8], w1[8];
        #pragma unroll
        for (int ct = 0; ct < 8; ++ct) {
            w0[ct] = Wlin[ct * 16 + colb];
            w1[ct] = Wlin[F + ct * 16 + colb];
        }
        #pragma unroll
        for (int i = 0; i < 4; ++i) {
            float p0 = 0.f, p1 = 0.f;
            #pragma unroll
            for (int ct = 0; ct < 8; ++ct) {
                p0 += acc[ct][i] * w0[ct];
                p1 += acc[ct][i] * w1[ct];
            }
            #pragma unroll
            for (int off = 1; off < 16; off <<= 1) {
                p0 += __shfl_xor(p0, off);
                p1 += __shfl_xor(p1, off);
            }
            int row = r0 + rq * 4 + i;
            if (colb == 0 && row < N_NODES) {
                float a = p0 + blin[0];
                float b = p1 + blin[1];
                float m = fmaxf(a, b);
                float lse = m + logf(expf(a - m) + expf(b - m));
                out[(size_t)row * 2 + 0] = a - lse;
                out[(size_t)row * 2 + 1] = b - lse;
            }
        }
    }
}

extern "C" void kernel_launch(void* const* d_in, const int* in_sizes, int n_in,
                              void* d_out, int out_size, void* d_ws, size_t ws_size,
                              hipStream_t stream) {
    const float* x    = (const float*)d_in[0];
    const int*   ei   = (const int*)d_in[1];     // [2][N_EDGES] int32
    const float* W1l  = (const float*)d_in[2];
    const float* b1l  = (const float*)d_in[3];
    const float* W1r  = (const float*)d_in[4];
    const float* W2l  = (const float*)d_in[5];
    const float* b2l  = (const float*)d_in[6];
    const float* W2r  = (const float*)d_in[7];
    const float* Wlin = (const float*)d_in[8];
    const float* blin = (const float*)d_in[9];
    float* out = (float*)d_out;

    const int* src = ei;
    const int* dst = ei + N_EDGES;

    char* ws = (char*)d_ws;
    int*            tails  = (int*)ws;                              // 800 B (pad 4 KB)
    unsigned int*   bEdge  = (unsigned int*)(ws + 4096);            // 3,686,400 B
    int*            cnt    = (int*)(ws + 3694592);                  // 200,000 B
    unsigned short* nbr    = (unsigned short*)(ws + 3895296);       // 6,400,000 B
    unsigned short* xb     = (unsigned short*)(ws + 10296320);      // 12.8 MB
    unsigned short* h1b    = (unsigned short*)(ws + 23097344);      // 12.8 MB
    unsigned short* aggb   = (unsigned short*)(ws + 35898368);      // 12.8 MB
    unsigned short* P1     = (unsigned short*)(ws + 48699392);      // 64 KB
    unsigned short* P2     = (unsigned short*)(ws + 48764928);      // 64 KB
    unsigned char*  xq     = (unsigned char*)(ws + 48830464);       // 6.4 MB
    unsigned char*  h1q    = (unsigned char*)(ws + 55230464);       // 6.4 MB
    float*          xscale = (float*)(ws + 61630464);               // 200 KB
    float*          h1scale= (float*)(ws + 61830464);               // 200 KB

    hipMemsetAsync(tails, 0, NBUCK * sizeof(int), stream);

    prep1<<<EDGE_BLKS + CVT_BLKS + 32, 256, 0, stream>>>(x, src, dst, W1l, W1r, W2l, W2r,
                                                         xb, xq, xscale, tails, bEdge, P1, P2);
    ell_build<<<NBUCK, 256, 0, stream>>>(tails, bEdge, cnt, nbr);

    // layer 1
    aggregate_q<<<6250, 256, 0, stream>>>(xq, xscale, cnt, nbr, aggb);
    sage_gemm<<<782, 256, 0, stream>>>(aggb, xb, P1, b1l, h1b, h1q, h1scale,
                                       nullptr, nullptr, nullptr, 0);

    // layer 2 + fused head
    aggregate_q<<<6250, 256, 0, stream>>>(h1q, h1scale, cnt, nbr, aggb);
    sage_gemm<<<782, 256, 0, stream>>>(aggb, h1b, P2, b2l, nullptr, nullptr, nullptr,
                                       Wlin, blin, out, 1);
}

// Round 11
// 122.093 us; speedup vs baseline: 11.3946x; 1.0452x over previous
//
#include <hip/hip_runtime.h>
#include <math.h>

#define N_NODES 50000
#define N_EDGES 800000
#define F 128
#define ELL_CAP 64           // Poisson(16) tail: P(deg>=64) ~ e^-125 per node
#define NBUCK 196            // ceil(50000/256) buckets of 256 consecutive dst nodes
#define BIN_CAP 97           // per-block per-bin: mean 32, ~11 sigma; 97%32==1 -> no bank conflicts
#define BUCK_CAP 4608        // per-bucket total: mean 4096, ~8 sigma
#define EDGE_BLKS 125
#define EPR (N_EDGES / EDGE_BLKS)       // 6400 edges per edge-block
#define CVT_BLKS 6250                   // 8 rows per block

typedef __attribute__((ext_vector_type(8))) short short8;
typedef __attribute__((ext_vector_type(4))) float float4v;

__device__ inline unsigned short f2bf(float f) {
    unsigned int u = __builtin_bit_cast(unsigned int, f);
    u += 0x7FFF + ((u >> 16) & 1);          // RNE
    return (unsigned short)(u >> 16);
}
__device__ inline float bf2f_lo(unsigned int u) {
    return __builtin_bit_cast(float, u << 16);
}
__device__ inline float bf2f_hi(unsigned int u) {
    return __builtin_bit_cast(float, u & 0xFFFF0000u);
}
__device__ inline float i8f(unsigned int u, int k) {       // sign-extend byte k -> float
    return (float)((signed char)(u >> (k * 8)));
}

// ---------------- prep1: single-pass edge binning (196 LDS bins) | cvt+quant | pack ----------------
// Edge blocks FIRST (their LDS-atomic latency overlaps the streaming cvt blocks).
// Each edge block scans its 6400-edge chunk ONCE, bins into 196 LDS bins
// (bucket = dst>>8), then flushes each bin as one reserved contiguous run.
__global__ __launch_bounds__(256) void prep1(const float* __restrict__ x,
                                             const int* __restrict__ src,
                                             const int* __restrict__ dst,
                                             const float* __restrict__ W1l,
                                             const float* __restrict__ W1r,
                                             const float* __restrict__ W2l,
                                             const float* __restrict__ W2r,
                                             unsigned short* __restrict__ xb,
                                             unsigned char* __restrict__ xq,
                                             float* __restrict__ xscale,
                                             int* __restrict__ tails,
                                             unsigned int* __restrict__ bucketEdges,
                                             unsigned short* __restrict__ P1,
                                             unsigned short* __restrict__ P2) {
    int blk = blockIdx.x;
    int tid = threadIdx.x;
    if (blk < EDGE_BLKS) {
        __shared__ int bin_cnt[NBUCK];
        __shared__ unsigned int bins[NBUCK * BIN_CAP];    // 76,048 B
        for (int i = tid; i < NBUCK; i += 256) bin_cnt[i] = 0;
        __syncthreads();
        int base = blk * EPR;
        for (int i = tid; i < EPR; i += 256) {
            int d = dst[base + i];
            int s = src[base + i];
            int lb = d >> 8;                              // 0..195
            int pos = atomicAdd(&bin_cnt[lb], 1);
            if (pos < BIN_CAP)
                bins[lb * BIN_CAP + pos] = ((unsigned int)(d & 255) << 16) | (unsigned int)s;
        }
        __syncthreads();
        if (tid < NBUCK) {
            int c = bin_cnt[tid]; if (c > BIN_CAP) c = BIN_CAP;
            int rb = atomicAdd(&tails[tid], c);
            unsigned int* dp = bucketEdges + (size_t)tid * BUCK_CAP;
            for (int i = 0; i < c; ++i) {
                int p = rb + i;
                if (p < BUCK_CAP) dp[p] = bins[tid * BIN_CAP + i];
            }
        }
    } else if (blk < EDGE_BLKS + CVT_BLKS) {
        // one row per 32-lane half-wave: bf16 copy + int8 row-quant (per-row absmax)
        int row = (blk - EDGE_BLKS) * 8 + (tid >> 5);
        int hl = tid & 31;
        float4 v = ((const float4*)x)[row * 32 + hl];
        float m = fmaxf(fmaxf(fabsf(v.x), fabsf(v.y)), fmaxf(fabsf(v.z), fabsf(v.w)));
        #pragma unroll
        for (int off = 1; off < 32; off <<= 1) m = fmaxf(m, __shfl_xor(m, off));
        float inv = m > 0.f ? 127.f / m : 0.f;
        int q0 = (int)rintf(v.x * inv), q1 = (int)rintf(v.y * inv);
        int q2 = (int)rintf(v.z * inv), q3 = (int)rintf(v.w * inv);
        unsigned int qp = (q0 & 255) | ((q1 & 255) << 8) | ((q2 & 255) << 16) | ((q3 & 255) << 24);
        ((unsigned int*)xq)[row * 32 + hl] = qp;
        unsigned int p0 = (unsigned int)f2bf(v.x) | ((unsigned int)f2bf(v.y) << 16);
        unsigned int p1 = (unsigned int)f2bf(v.z) | ((unsigned int)f2bf(v.w) << 16);
        ((uint2*)xb)[row * 32 + hl] = make_uint2(p0, p1);
        if (hl == 0) xscale[row] = m * (1.f / 127.f);
    } else {
        int pblk = blk - (EDGE_BLKS + CVT_BLKS);          // 0..31
        int t = (pblk & 15) * 256 + tid;                  // 0..4095
        int lane = t & 63;
        int ct = (t >> 6) & 7;
        int ks = t >> 9;                                  // 0..7
        const float* Wl = (pblk < 16) ? W1l : W2l;
        const float* Wr = (pblk < 16) ? W1r : W2r;
        unsigned short* P = (pblk < 16) ? P1 : P2;
        int col = ct * 16 + (lane & 15);
        int kbase = (ks & 3) * 32 + (lane >> 4) * 8;
        const float* W = (ks < 4) ? Wl : Wr;
        unsigned short* dp = P + (size_t)t * 8;
        #pragma unroll
        for (int j = 0; j < 8; ++j) dp[j] = f2bf(W[col * F + kbase + j]);
    }
}

// ---------------- prep2: per-bucket ELL build in LDS, dense streamed output ----------------
__global__ __launch_bounds__(256) void ell_build(const int* __restrict__ tails,
                                                 const unsigned int* __restrict__ bucketEdges,
                                                 int* __restrict__ cnt,
                                                 unsigned short* __restrict__ nbr) {
    __shared__ int cl[256];
    __shared__ unsigned short ell[256 * ELL_CAP];         // 32 KB
    int b = blockIdx.x;                                   // 0..195
    int tid = threadIdx.x;
    cl[tid] = 0;
    __syncthreads();
    int T = tails[b]; if (T > BUCK_CAP) T = BUCK_CAP;
    const unsigned int* eb = bucketEdges + (size_t)b * BUCK_CAP;
    for (int i = tid; i < T; i += 256) {
        unsigned int rec = eb[i];
        int nib = rec >> 16;
        int pos = atomicAdd(&cl[nib], 1);
        if (pos < ELL_CAP) ell[nib * ELL_CAP + pos] = (unsigned short)(rec & 0xFFFFu);
    }
    __syncthreads();
    int nb0 = b * 256;
    int nn = N_NODES - nb0; if (nn > 256) nn = 256;        // 256 (last bucket: 80)
    if (tid < nn) cnt[nb0 + tid] = cl[tid];
    const uint4* s4 = (const uint4*)ell;
    uint4* d4 = (uint4*)(nbr + (size_t)nb0 * ELL_CAP);
    int n4 = nn * (ELL_CAP * 2 / 16);                      // nn * 8 uint4s
    for (int i = tid; i < n4; i += 256) d4[i] = s4[i];
}

// ---------------- mean aggregation over int8-quantized rows: 2 nodes/wave, 4-row unroll ----------------
// Per row: 32 lanes x 4B (int8x4) = 128B coalesced gather + one 4B scale broadcast.
__global__ __launch_bounds__(256) void aggregate_q(const unsigned char* __restrict__ Xq,
                                                   const float* __restrict__ xs,
                                                   const int* __restrict__ cnt,
                                                   const unsigned short* __restrict__ nbr,
                                                   unsigned short* __restrict__ agg) {
    int tid = threadIdx.x;
    int wave = tid >> 6;
    int lane = tid & 63;
    int half = lane >> 5;
    int hl = lane & 31;
    int node = blockIdx.x * 8 + wave * 2 + half;   // 6250*8 = 50000 exact

    int degt = cnt[node];
    int deg = degt < ELL_CAP ? degt : ELL_CAP;
    const unsigned short* nb = nbr + node * ELL_CAP;
    const unsigned int* Xu = (const unsigned int*)Xq;

    float a0 = 0.f, a1 = 0.f, a2 = 0.f, a3 = 0.f;
    int s = 0;
    for (; s + 4 <= deg; s += 4) {
        ushort4 nv = *(const ushort4*)(nb + s);
        unsigned int g0 = Xu[nv.x * 32 + hl]; float s0 = xs[nv.x];
        unsigned int g1 = Xu[nv.y * 32 + hl]; float s1 = xs[nv.y];
        unsigned int g2 = Xu[nv.z * 32 + hl]; float s2 = xs[nv.z];
        unsigned int g3 = Xu[nv.w * 32 + hl]; float s3 = xs[nv.w];
        a0 += i8f(g0, 0) * s0 + i8f(g1, 0) * s1 + i8f(g2, 0) * s2 + i8f(g3, 0) * s3;
        a1 += i8f(g0, 1) * s0 + i8f(g1, 1) * s1 + i8f(g2, 1) * s2 + i8f(g3, 1) * s3;
        a2 += i8f(g0, 2) * s0 + i8f(g1, 2) * s1 + i8f(g2, 2) * s2 + i8f(g3, 2) * s3;
        a3 += i8f(g0, 3) * s0 + i8f(g1, 3) * s1 + i8f(g2, 3) * s2 + i8f(g3, 3) * s3;
    }
    for (; s < deg; ++s) {
        int v = nb[s];
        unsigned int g = Xu[v * 32 + hl]; float sc = xs[v];
        a0 += i8f(g, 0) * sc; a1 += i8f(g, 1) * sc;
        a2 += i8f(g, 2) * sc; a3 += i8f(g, 3) * sc;
    }
    float inv = 1.0f / (float)(degt > 0 ? degt : 1);
    unsigned int p0 = (unsigned int)f2bf(a0 * inv) | ((unsigned int)f2bf(a1 * inv) << 16);
    unsigned int p1 = (unsigned int)f2bf(a2 * inv) | ((unsigned int)f2bf(a3 * inv) << 16);
    *(uint2*)(agg + (size_t)node * F + hl * 4) = make_uint2(p0, p1);
}

// ---------------- fused SAGE layer: relu([A|B] @ Wcat + bias), MFMA, no LDS ----------------
// mode 0: write bf16 Hout + int8 Hq/Hscale.  mode 1: fused head + log_softmax -> out.
__global__ __launch_bounds__(256) void sage_gemm(const unsigned short* __restrict__ Abf,
                                                 const unsigned short* __restrict__ Bbf,
                                                 const unsigned short* __restrict__ Pw,
                                                 const float* __restrict__ bias,
                                                 unsigned short* __restrict__ Hout,
                                                 unsigned char* __restrict__ Hq,
                                                 float* __restrict__ Hscale,
                                                 const float* __restrict__ Wlin,
                                                 const float* __restrict__ blin,
                                                 float* __restrict__ out, int mode) {
    int lane = threadIdx.x & 63;
    int wave = threadIdx.x >> 6;
    int r0 = blockIdx.x * 64 + wave * 16;
    int rowA = r0 + (lane & 15);
    if (rowA >= N_NODES) rowA = N_NODES - 1;        // clamp; writes are guarded
    int kg = lane >> 4;

    short8 af[4], bfr[4];
    const short8* Ap = (const short8*)(Abf + (size_t)rowA * F);
    const short8* Bp = (const short8*)(Bbf + (size_t)rowA * F);
    #pragma unroll
    for (int ks = 0; ks < 4; ++ks) {
        af[ks]  = Ap[ks * 4 + kg];
        bfr[ks] = Bp[ks * 4 + kg];
    }

    const short8* Wp = (const short8*)Pw;
    float4v acc[8];
    #pragma unroll
    for (int ct = 0; ct < 8; ++ct) {
        float4v c = {0.f, 0.f, 0.f, 0.f};
        #pragma unroll
        for (int ks = 0; ks < 4; ++ks)
            c = __builtin_amdgcn_mfma_f32_16x16x32_bf16(af[ks], Wp[(ks * 8 + ct) * 64 + lane], c, 0, 0, 0);
        #pragma unroll
        for (int ks = 0; ks < 4; ++ks)
            c = __builtin_amdgcn_mfma_f32_16x16x32_bf16(bfr[ks], Wp[((ks + 4) * 8 + ct) * 64 + lane], c, 0, 0, 0);
        acc[ct] = c;
    }

    int colb = lane & 15;
    int rq = lane >> 4;
    #pragma unroll
    for (int ct = 0; ct < 8; ++ct) {
        float bv = bias[ct * 16 + colb];
        #pragma unroll
        for (int i = 0; i < 4; ++i)
            acc[ct][i] = fmaxf(acc[ct][i] + bv, 0.f);
    }

    if (mode == 0) {
        #pragma unroll
        for (int ct = 0; ct < 8; ++ct) {
            #pragma unroll
            for (int i = 0; i < 4; ++i) {
                int row = r0 + rq * 4 + i;
                if (row < N_NODES)
                    Hout[(size_t)row * F + ct * 16 + colb] = f2bf(acc[ct][i]);
            }
        }
        // int8 row-quant: absmax over 8 local cols, then 16-lane (colb-group) reduce
        #pragma unroll
        for (int i = 0; i < 4; ++i) {
            float m = 0.f;
            #pragma unroll
            for (int ct = 0; ct < 8; ++ct) m = fmaxf(m, acc[ct][i]);   // relu'd -> >=0
            #pragma unroll
            for (int off = 1; off < 16; off <<= 1) m = fmaxf(m, __shfl_xor(m, off));
            float inv = m > 0.f ? 127.f / m : 0.f;
            int row = r0 + rq * 4 + i;
            if (row < N_NODES) {
                if (colb == 0) Hscale[row] = m * (1.f / 127.f);
                #pragma unroll
                for (int ct = 0; ct < 8; ++ct) {
                    int q = (int)rintf(acc[ct][i] * inv);
                    Hq[(size_t)row * F + ct * 16 + colb] = (unsigned char)q;
                }
            }
        }
    } else {
        float w0[8], w1[8];
        #pragma unroll
        for (int ct = 0; ct < 8; ++ct) {
            w0[ct] = Wlin[ct * 16 + colb];
            w1[ct] = Wlin[F + ct * 16 + colb];
        }
        #pragma unroll
        for (int i = 0; i < 4; ++i) {
            float p0 = 0.f, p1 = 0.f;
            #pragma unroll
            for (int ct = 0; ct < 8; ++ct) {
                p0 += acc[ct][i] * w0[ct];
                p1 += acc[ct][i] * w1[ct];
            }
            #pragma unroll
            for (int off = 1; off < 16; off <<= 1) {
                p0 += __shfl_xor(p0, off);
                p1 += __shfl_xor(p1, off);
            }
            int row = r0 + rq * 4 + i;
            if (colb == 0 && row < N_NODES) {
                float a = p0 + blin[0];
                float b = p1 + blin[1];
                float m = fmaxf(a, b);
                float lse = m + logf(expf(a - m) + expf(b - m));
                out[(size_t)row * 2 + 0] = a - lse;
                out[(size_t)row * 2 + 1] = b - lse;
            }
        }
    }
}

extern "C" void kernel_launch(void* const* d_in, const int* in_sizes, int n_in,
                              void* d_out, int out_size, void* d_ws, size_t ws_size,
                              hipStream_t stream) {
    const float* x    = (const float*)d_in[0];
    const int*   ei   = (const int*)d_in[1];     // [2][N_EDGES] int32
    const float* W1l  = (const float*)d_in[2];
    const float* b1l  = (const float*)d_in[3];
    const float* W1r  = (const float*)d_in[4];
    const float* W2l  = (const float*)d_in[5];
    const float* b2l  = (const float*)d_in[6];
    const float* W2r  = (const float*)d_in[7];
    const float* Wlin = (const float*)d_in[8];
    const float* blin = (const float*)d_in[9];
    float* out = (float*)d_out;

    const int* src = ei;
    const int* dst = ei + N_EDGES;

    char* ws = (char*)d_ws;
    int*            tails  = (int*)ws;                              // 784 B (pad 4 KB)
    unsigned int*   bEdge  = (unsigned int*)(ws + 4096);            // 196*4608*4 = 3,612,672 B
    int*            cnt    = (int*)(ws + 3620864);                  // 200,000 B
    unsigned short* nbr    = (unsigned short*)(ws + 3821568);       // 6,400,000 B
    unsigned short* xb     = (unsigned short*)(ws + 10221568);      // 12.8 MB
    unsigned short* h1b    = (unsigned short*)(ws + 23021568);      // 12.8 MB
    unsigned short* aggb   = (unsigned short*)(ws + 35821568);      // 12.8 MB
    unsigned short* P1     = (unsigned short*)(ws + 48621568);      // 64 KB
    unsigned short* P2     = (unsigned short*)(ws + 48687104);      // 64 KB
    unsigned char*  xq     = (unsigned char*)(ws + 48752640);       // 6.4 MB
    unsigned char*  h1q    = (unsigned char*)(ws + 55152640);       // 6.4 MB
    float*          xscale = (float*)(ws + 61552640);               // 200 KB
    float*          h1scale= (float*)(ws + 61752640);               // 200 KB

    hipMemsetAsync(tails, 0, NBUCK * sizeof(int), stream);

    prep1<<<EDGE_BLKS + CVT_BLKS + 32, 256, 0, stream>>>(x, src, dst, W1l, W1r, W2l, W2r,
                                                         xb, xq, xscale, tails, bEdge, P1, P2);
    ell_build<<<NBUCK, 256, 0, stream>>>(tails, bEdge, cnt, nbr);

    // layer 1
    aggregate_q<<<6250, 256, 0, stream>>>(xq, xscale, cnt, nbr, aggb);
    sage_gemm<<<782, 256, 0, stream>>>(aggb, xb, P1, b1l, h1b, h1q, h1scale,
                                       nullptr, nullptr, nullptr, 0);

    // layer 2 + fused head
    aggregate_q<<<6250, 256, 0, stream>>>(h1q, h1scale, cnt, nbr, aggb);
    sage_gemm<<<782, 256, 0, stream>>>(aggb, h1b, P2, b2l, nullptr, nullptr, nullptr,
                                       Wlin, blin, out, 1);
}